// Round 6
// baseline (195.809 us; speedup 1.0000x reference)
//
#include <hip/hip_runtime.h>

// Problem dims (compile-time)
#define BATCH 1024
#define NELEC 64
#define DF    32     // backflow feature dim D
#define NION  16
#define NORB  32
#define NE    32     // NELEC / NSPIN
#define NSB   2048   // NSPIN * BATCH
#define MG_FLOATS (2*NION*6*NORB)    // 6144 floats
#define WS_NEEDED ((size_t)MG_FLOATS * 4)

// Raw barrier that does NOT drain vmcnt: global stores stay in flight across
// it; only LDS (lgkm) ordering is enforced. sched_barrier pins codegen
// (rule: compiler may hoist LDS-dependent ops past inline-asm waitcnt).
__device__ __forceinline__ void lgkm_barrier() {
    __builtin_amdgcn_sched_barrier(0);
    asm volatile("s_waitcnt lgkmcnt(0)" ::: "memory");
    __builtin_amdgcn_s_barrier();
    __builtin_amdgcn_sched_barrier(0);
}

// ---------------------------------------------------------------------------
// K0: Gram matrices, SoA layout  Mg[s][i][m][o], m in 0..5 =
//     {m00, m11, m22, 2*m01, 2*m02, 2*m12},  m_dd' = sum_e A[d,e]*A[d',e]
// ---------------------------------------------------------------------------
__global__ __launch_bounds__(256) void k0_gram(
    const float* __restrict__ W_env,   // (2, NION, 3, NORB, 3)
    float* __restrict__ Mg)            // (2, NION, 6, NORB)
{
    int id = blockIdx.x * 256 + threadIdx.x;
    if (id >= 2 * NION * NORB) return;
    int s = id >> 9, rem = id & 511, i = rem >> 5, o = rem & 31;
    const float* base = W_env + ((size_t)((s*NION + i) * 3) * NORB + o) * 3;
    float a0[3], a1[3], a2[3];
    #pragma unroll
    for (int e = 0; e < 3; ++e) {
        a0[e] = base[e];           // d-stride = NORB*3 = 96
        a1[e] = base[96 + e];
        a2[e] = base[192 + e];
    }
    float* out = Mg + ((size_t)(s*NION + i) * 6) * NORB + o;
    out[0*NORB] = a0[0]*a0[0] + a0[1]*a0[1] + a0[2]*a0[2];
    out[1*NORB] = a1[0]*a1[0] + a1[1]*a1[1] + a1[2]*a1[2];
    out[2*NORB] = a2[0]*a2[0] + a2[1]*a2[1] + a2[2]*a2[2];
    out[3*NORB] = 2.f*(a0[0]*a1[0] + a0[1]*a1[1] + a0[2]*a1[2]);
    out[4*NORB] = 2.f*(a0[0]*a2[0] + a0[1]*a2[1] + a0[2]*a2[2]);
    out[5*NORB] = 2.f*(a1[0]*a2[0] + a1[1]*a2[1] + a1[2]*a2[2]);
}

// ---------------------------------------------------------------------------
// Fused pair kernel: one block = two walkers of one spin. Pipeline:
//   factors(w0) | B | stage r(w1) + GEMM(w1)->regs + stores(w0) | B |
//   envelope(w1)+factor-writes (overlaps w0 store drain) | B | stores(w1)
// Barriers are lgkm-only so stores never drain at a phase boundary.
// ---------------------------------------------------------------------------
__global__ __launch_bounds__(256, 4) void deq_fused_pair(
    const float* __restrict__ x,      // (B, NELEC, D)
    const float* __restrict__ r_ei,   // (B, NELEC, NION, 3)
    const float* __restrict__ W_orb,  // (2, 2D, NORB)
    const float* __restrict__ b_orb,  // (2, NORB)
    const float* __restrict__ w_ion,  // (2, NION)
    const float* __restrict__ Mg,     // (2, NION, 6, NORB)
    float* __restrict__ out)          // (2, B, NE, NE, NORB)
{
    __shared__ float sworb[2*DF*NORB];   // 8 KB  [d(64)][o(32)]
    __shared__ float sM[NION*6*NORB];    // 12 KB [i][m][o]
    __shared__ float sr[NE*48];          // 6 KB  [n][48] (uniform half-wave reads)
    __shared__ float sU[NE*NORB];        // 4 KB
    __shared__ float sE[NE*NORB];        // 4 KB
    __shared__ float sW[NE*NORB];        // 4 KB
    __shared__ float swion[NION];        // total 38.1 KB -> 4 blocks/CU

    const int t   = threadIdx.x;
    const int blk = blockIdx.x;
    const int s   = blk >> 9;
    const int b0  = (blk & 511) * 2;

    // ---- stage tables + r(w0) ----
    {
        const float4* g = (const float4*)(W_orb + (size_t)s * 2*DF*NORB);
        float4* d = (float4*)sworb;
        d[t] = g[t]; d[t + 256] = g[t + 256];
    }
    {
        const float4* g = (const float4*)(Mg + (size_t)s * NION*6*NORB);
        float4* d = (float4*)sM;
        d[t] = g[t]; d[t + 256] = g[t + 256]; d[t + 512] = g[t + 512];
    }
    {
        const float4* g = (const float4*)(r_ei + ((size_t)b0*NELEC + s*NE) * (NION*3));
        float4* d = (float4*)sr;
        d[t] = g[t];
        if (t < 128) d[t + 256] = g[t + 256];
    }
    if (t < NION) swion[t] = w_ion[s*NION + t];
    __syncthreads();   // one full sync at start is fine (nothing in flight)

    const int o  = t & 31;         // orbital lane (factor phases)
    const int ng = t >> 5;         // electron group, 4 electrons
    const int n0 = ng * 4;
    const int ii = t >> 3;         // electron (epilogue)
    const int o0 = (t & 7) * 4;    // orbital quad (epilogue)
    const float bo = b_orb[s*NORB + o];

    // ================= factors(w0) =================
    {
        float u[4] = {0,0,0,0}, v[4] = {0,0,0,0}, ea[4] = {0,0,0,0};
        const float* xrow = x + ((size_t)b0*NELEC + s*NE + n0) * DF;
        #pragma unroll
        for (int db = 0; db < 8; ++db) {
            float4 xa[4];
            #pragma unroll
            for (int e = 0; e < 4; ++e)
                xa[e] = *(const float4*)(xrow + e*DF + db*4);
            #pragma unroll
            for (int k = 0; k < 4; ++k) {
                const int d = db*4 + k;
                const float w0 = sworb[d*NORB + o];
                const float w1 = sworb[(DF + d)*NORB + o];
                #pragma unroll
                for (int e = 0; e < 4; ++e) {
                    const float xk = (&xa[e].x)[k];
                    u[e] += xk * w0;
                    v[e] += xk * w1;
                }
            }
        }
        #pragma unroll 4
        for (int i = 0; i < NION; ++i) {
            const float m0 = sM[(i*6 + 0)*NORB + o];
            const float m1 = sM[(i*6 + 1)*NORB + o];
            const float m2 = sM[(i*6 + 2)*NORB + o];
            const float m3 = sM[(i*6 + 3)*NORB + o];
            const float m4 = sM[(i*6 + 4)*NORB + o];
            const float m5 = sM[(i*6 + 5)*NORB + o];
            const float wi = swion[i];
            #pragma unroll
            for (int e = 0; e < 4; ++e) {
                const float r0 = sr[(n0+e)*48 + i*3 + 0];
                const float r1 = sr[(n0+e)*48 + i*3 + 1];
                const float r2 = sr[(n0+e)*48 + i*3 + 2];
                float d2 = m0*(r0*r0) + m1*(r1*r1) + m2*(r2*r2)
                         + m3*(r0*r1) + m4*(r0*r2) + m5*(r1*r2);
                ea[e] += wi * __expf(-sqrtf(fmaxf(d2, 0.f)));
            }
        }
        #pragma unroll
        for (int e = 0; e < 4; ++e) {
            const int idx = (n0+e)*NORB + o;
            sU[idx] = u[e];
            sE[idx] = ea[e];
            sW[idx] = (v[e] + bo) * ea[e];
        }
    }
    lgkm_barrier();

    // ======= stage r(w1) + GEMM(w1)->regs + epilogue-stores(w0) =======
    {
        const float4* g = (const float4*)(r_ei + ((size_t)(b0+1)*NELEC + s*NE) * (NION*3));
        float4* d = (float4*)sr;
        d[t] = g[t];
        if (t < 128) d[t + 256] = g[t + 256];
    }

    float u1[4] = {0,0,0,0}, v1[4] = {0,0,0,0};
    {
        const float* xrow = x + ((size_t)(b0+1)*NELEC + s*NE + n0) * DF;
        #pragma unroll
        for (int db = 0; db < 8; ++db) {
            float4 xa[4];
            #pragma unroll
            for (int e = 0; e < 4; ++e)
                xa[e] = *(const float4*)(xrow + e*DF + db*4);
            #pragma unroll
            for (int k = 0; k < 4; ++k) {
                const int d = db*4 + k;
                const float w0 = sworb[d*NORB + o];
                const float w1 = sworb[(DF + d)*NORB + o];
                #pragma unroll
                for (int e = 0; e < 4; ++e) {
                    const float xk = (&xa[e].x)[k];
                    u1[e] += xk * w0;
                    v1[e] += xk * w1;
                }
            }
        }
    }
    // pin: all x(w1) loads issue BEFORE any w0 store (in-order vmcnt retire)
    __builtin_amdgcn_sched_barrier(0);

    {   // epilogue walker 0: out[p,i,o] = U[p,o]*E[i,o] + W[i,o]
        const float4 e4 = *(const float4*)(sE + ii*NORB + o0);
        const float4 w4 = *(const float4*)(sW + ii*NORB + o0);
        float4* outp = (float4*)(out + (size_t)(s*BATCH + b0) * (NE*NE*NORB));
        #pragma unroll
        for (int p = 0; p < NE; ++p) {
            const float4 u4 = *(const float4*)(sU + p*NORB + o0);
            float4 rr;
            rr.x = u4.x*e4.x + w4.x;
            rr.y = u4.y*e4.y + w4.y;
            rr.z = u4.z*e4.z + w4.z;
            rr.w = u4.w*e4.w + w4.w;
            outp[p*256 + t] = rr;   // 4 KB contiguous per iter
        }
    }
    lgkm_barrier();

    // ======= envelope(w1) + factor writes (overlaps w0 store drain) =======
    {
        float ea[4] = {0,0,0,0};
        #pragma unroll 4
        for (int i = 0; i < NION; ++i) {
            const float m0 = sM[(i*6 + 0)*NORB + o];
            const float m1 = sM[(i*6 + 1)*NORB + o];
            const float m2 = sM[(i*6 + 2)*NORB + o];
            const float m3 = sM[(i*6 + 3)*NORB + o];
            const float m4 = sM[(i*6 + 4)*NORB + o];
            const float m5 = sM[(i*6 + 5)*NORB + o];
            const float wi = swion[i];
            #pragma unroll
            for (int e = 0; e < 4; ++e) {
                const float r0 = sr[(n0+e)*48 + i*3 + 0];
                const float r1 = sr[(n0+e)*48 + i*3 + 1];
                const float r2 = sr[(n0+e)*48 + i*3 + 2];
                float d2 = m0*(r0*r0) + m1*(r1*r1) + m2*(r2*r2)
                         + m3*(r0*r1) + m4*(r0*r2) + m5*(r1*r2);
                ea[e] += wi * __expf(-sqrtf(fmaxf(d2, 0.f)));
            }
        }
        #pragma unroll
        for (int e = 0; e < 4; ++e) {
            const int idx = (n0+e)*NORB + o;
            sU[idx] = u1[e];
            sE[idx] = ea[e];
            sW[idx] = (v1[e] + bo) * ea[e];
        }
    }
    lgkm_barrier();

    {   // epilogue walker 1
        const float4 e4 = *(const float4*)(sE + ii*NORB + o0);
        const float4 w4 = *(const float4*)(sW + ii*NORB + o0);
        float4* outp = (float4*)(out + (size_t)(s*BATCH + b0 + 1) * (NE*NE*NORB));
        #pragma unroll
        for (int p = 0; p < NE; ++p) {
            const float4 u4 = *(const float4*)(sU + p*NORB + o0);
            float4 rr;
            rr.x = u4.x*e4.x + w4.x;
            rr.y = u4.y*e4.y + w4.y;
            rr.z = u4.z*e4.z + w4.z;
            rr.w = u4.w*e4.w + w4.w;
            outp[p*256 + t] = rr;
        }
    }
}

// ---------------------------------------------------------------------------
// Fallback: proven single fused kernel (used only if ws is too small)
// ---------------------------------------------------------------------------
__global__ __launch_bounds__(256) void deq_orbital_fused(
    const float* __restrict__ x, const float* __restrict__ r_ei,
    const float* __restrict__ W_orb, const float* __restrict__ b_orb,
    const float* __restrict__ W_env, const float* __restrict__ w_ion,
    float* __restrict__ out)
{
    __shared__ float sx[NE][DF];
    __shared__ float sworb[2*DF][NORB];
    __shared__ float sr[NE][NION*3];
    __shared__ float swe[NION*3*NORB*3];
    __shared__ float sU[NE][NORB];
    __shared__ float sV[NE][NORB];
    __shared__ float sE[NE][NORB];
    __shared__ float sb[NORB];
    __shared__ float swion[NION];

    const int t   = threadIdx.x;
    const int blk = blockIdx.x;
    const int s   = blk >> 10;
    const int b   = blk & (BATCH - 1);

    {
        const float4* xg = (const float4*)(x + (size_t)(b*NELEC + s*NE) * DF);
        ((float4*)&sx[0][0])[t] = xg[t];
    }
    {
        const float4* wg = (const float4*)(W_orb + (size_t)s * 2*DF*NORB);
        float4* d = (float4*)&sworb[0][0];
        d[t] = wg[t]; d[t + 256] = wg[t + 256];
    }
    {
        const float4* rg = (const float4*)(r_ei + (size_t)(b*NELEC + s*NE) * NION * 3);
        float4* d = (float4*)&sr[0][0];
        d[t] = rg[t];
        if (t < 128) d[t + 256] = rg[t + 256];
    }
    {
        const float4* weg = (const float4*)(W_env + (size_t)s * NION*3*NORB*3);
        float4* d = (float4*)swe;
        for (int j = t; j < 1152; j += 256) d[j] = weg[j];
    }
    if (t < NORB) sb[t]    = b_orb[s*NORB + t];
    if (t < NION) swion[t] = w_ion[s*NION + t];
    __syncthreads();

    const int o  = t & 31;
    const int ng = t >> 5;
    float u_acc[4], v_acc[4];
    #pragma unroll
    for (int uu = 0; uu < 4; ++uu) { u_acc[uu] = 0.f; v_acc[uu] = 0.f; }
    #pragma unroll
    for (int d = 0; d < DF; ++d) {
        const float w0 = sworb[d][o];
        const float w1 = sworb[DF + d][o];
        #pragma unroll
        for (int uu = 0; uu < 4; ++uu) {
            const float xv = sx[ng*4 + uu][d];
            u_acc[uu] += xv * w0;
            v_acc[uu] += xv * w1;
        }
    }
    #pragma unroll
    for (int uu = 0; uu < 4; ++uu) {
        sU[ng*4 + uu][o] = u_acc[uu];
        sV[ng*4 + uu][o] = v_acc[uu];
    }
    #pragma unroll
    for (int uu = 0; uu < 4; ++uu) {
        const int nn = ng*4 + uu;
        float acc = 0.f;
        #pragma unroll
        for (int i = 0; i < NION; ++i) {
            const float r0 = sr[nn][i*3 + 0];
            const float r1 = sr[nn][i*3 + 1];
            const float r2 = sr[nn][i*3 + 2];
            const float* wp = &swe[i*3*NORB*3 + o*3];
            const float s0 = r0*wp[0] + r1*wp[NORB*3    ] + r2*wp[2*NORB*3    ];
            const float s1 = r0*wp[1] + r1*wp[NORB*3 + 1] + r2*wp[2*NORB*3 + 1];
            const float s2 = r0*wp[2] + r1*wp[NORB*3 + 2] + r2*wp[2*NORB*3 + 2];
            const float dist = sqrtf(s0*s0 + s1*s1 + s2*s2);
            acc += __expf(-dist) * swion[i];
        }
        sE[nn][o] = acc;
        sV[nn][o] = (v_acc[uu] + sb[o]) * acc;
    }
    __syncthreads();

    const int io = t >> 3;
    const int o0 = (t & 7) * 4;
    const float4 e4 = *(const float4*)&sE[io][o0];
    const float4 w4 = *(const float4*)&sV[io][o0];
    float4* outp = (float4*)(out + (size_t)blk * (NE*NE*NORB));
    #pragma unroll
    for (int p = 0; p < NE; ++p) {
        const float4 u4 = *(const float4*)&sU[p][o0];
        float4 r;
        r.x = u4.x*e4.x + w4.x;
        r.y = u4.y*e4.y + w4.y;
        r.z = u4.z*e4.z + w4.z;
        r.w = u4.w*e4.w + w4.w;
        outp[p*256 + t] = r;
    }
}

extern "C" void kernel_launch(void* const* d_in, const int* in_sizes, int n_in,
                              void* d_out, int out_size, void* d_ws, size_t ws_size,
                              hipStream_t stream) {
    const float* x     = (const float*)d_in[0];
    const float* r_ei  = (const float*)d_in[1];
    const float* W_orb = (const float*)d_in[2];
    const float* b_orb = (const float*)d_in[3];
    const float* W_env = (const float*)d_in[4];
    const float* w_ion = (const float*)d_in[5];
    float* out = (float*)d_out;

    if (ws_size >= WS_NEEDED) {
        float* Mg = (float*)d_ws;
        k0_gram<<<4, 256, 0, stream>>>(W_env, Mg);
        deq_fused_pair<<<1024, 256, 0, stream>>>(x, r_ei, W_orb, b_orb,
                                                 w_ion, Mg, out);
    } else {
        deq_orbital_fused<<<NSB, 256, 0, stream>>>(x, r_ei, W_orb, b_orb,
                                                   W_env, w_ion, out);
    }
}

// Round 7
// 87.489 us; speedup vs baseline: 2.2381x; 2.2381x over previous
//
#include <hip/hip_runtime.h>

// Problem dims (compile-time)
#define BATCH 1024
#define NELEC 64
#define DF    32     // backflow feature dim D
#define NION  16
#define NORB  32
#define NE    32     // NELEC / NSPIN
#define NSB   2048   // NSPIN * BATCH
#define FACT_FLOATS (NSB * NE * NORB)       // 2M floats = 8 MB per factor
#define M_PAD 8192                           // Gram region (6144 used)
#define WS_NEEDED ((size_t)(M_PAD + 3 * FACT_FLOATS) * 4)

// ---------------------------------------------------------------------------
// K0: Gram matrices, SoA layout  Mg[s][i][m][o], m in 0..5 =
//     {m00, m11, m22, 2*m01, 2*m02, 2*m12},  m_dd' = sum_e A[d,e]*A[d',e]
// ---------------------------------------------------------------------------
__global__ __launch_bounds__(256) void k0_gram(
    const float* __restrict__ W_env,   // (2, NION, 3, NORB, 3)
    float* __restrict__ Mg)            // (2, NION, 6, NORB)
{
    int id = blockIdx.x * 256 + threadIdx.x;
    if (id >= 2 * NION * NORB) return;
    int s = id >> 9, rem = id & 511, i = rem >> 5, o = rem & 31;
    const float* base = W_env + ((size_t)((s*NION + i) * 3) * NORB + o) * 3;
    float a0[3], a1[3], a2[3];
    #pragma unroll
    for (int e = 0; e < 3; ++e) {
        a0[e] = base[e];           // d-stride = NORB*3 = 96
        a1[e] = base[96 + e];
        a2[e] = base[192 + e];
    }
    float* out = Mg + ((size_t)(s*NION + i) * 6) * NORB + o;
    out[0*NORB] = a0[0]*a0[0] + a0[1]*a0[1] + a0[2]*a0[2];
    out[1*NORB] = a1[0]*a1[0] + a1[1]*a1[1] + a1[2]*a1[2];
    out[2*NORB] = a2[0]*a2[0] + a2[1]*a2[1] + a2[2]*a2[2];
    out[3*NORB] = 2.f*(a0[0]*a1[0] + a0[1]*a1[1] + a0[2]*a1[2]);
    out[4*NORB] = 2.f*(a0[0]*a2[0] + a0[1]*a2[1] + a0[2]*a2[2]);
    out[5*NORB] = 2.f*(a1[0]*a2[0] + a1[1]*a2[1] + a1[2]*a2[2]);
}

// ---------------------------------------------------------------------------
// K1: one (spin,walker) per block. Thread = (o = t&31, group ng = t>>5,
// electrons n0..n0+3). Tables (W_orb, Gram M) read b32 conflict-free across
// o-lanes; per-electron data (x, r) read b128 wave-uniform (broadcast).
// All in LDS: proven fastest issue pattern (R2 vs R4/R5 evidence).
// ---------------------------------------------------------------------------
__global__ __launch_bounds__(256) void k1_factors(
    const float* __restrict__ x,      // (B, NELEC, D)
    const float* __restrict__ r_ei,   // (B, NELEC, NION, 3)
    const float* __restrict__ W_orb,  // (2, 2D, NORB)
    const float* __restrict__ b_orb,  // (2, NORB)
    const float* __restrict__ w_ion,  // (2, NION)
    const float* __restrict__ Mg,     // (2, NION, 6, NORB)
    float* __restrict__ Uf, float* __restrict__ Ef, float* __restrict__ Wf)
{
    __shared__ float sworb[2*DF*NORB];   // 8 KB   [d(64)][o(32)]
    __shared__ float sM[NION*6*NORB];    // 12 KB  [i][m][o]
    __shared__ float sx[NE*DF];          // 4 KB   [n][32]
    __shared__ float sr[NE*48];          // 6 KB   [n][48]
    __shared__ float swion[NION];        // ~30.2 KB total

    const int t   = threadIdx.x;
    const int blk = blockIdx.x;
    const int s   = blk >> 10;
    const int b   = blk & (BATCH - 1);

    // ---- stage ----
    {
        const float4* g = (const float4*)(W_orb + (size_t)s * 2*DF*NORB);
        float4* d = (float4*)sworb;
        d[t] = g[t]; d[t + 256] = g[t + 256];
    }
    {
        const float4* g = (const float4*)(Mg + (size_t)s * NION*6*NORB);
        float4* d = (float4*)sM;
        d[t] = g[t]; d[t + 256] = g[t + 256]; d[t + 512] = g[t + 512];
    }
    {
        const float4* g = (const float4*)(x + (size_t)(b*NELEC + s*NE) * DF);
        ((float4*)sx)[t] = g[t];
    }
    {
        const float4* g = (const float4*)(r_ei + (size_t)(b*NELEC + s*NE) * (NION*3));
        float4* d = (float4*)sr;
        d[t] = g[t];
        if (t < 128) d[t + 256] = g[t + 256];
    }
    if (t < NION) swion[t] = w_ion[s*NION + t];
    __syncthreads();

    const int o  = t & 31;
    const int ng = t >> 5;
    const int n0 = ng * 4;

    // ---- GEMM: U, V.  x: b128 broadcast; W: b32, 32 distinct banks ----
    float u[4] = {0,0,0,0}, v[4] = {0,0,0,0};
    #pragma unroll
    for (int db = 0; db < 8; ++db) {
        float4 xa[4];
        #pragma unroll
        for (int e = 0; e < 4; ++e)
            xa[e] = *(const float4*)(sx + (n0 + e)*DF + db*4);
        #pragma unroll
        for (int k = 0; k < 4; ++k) {
            const int d = db*4 + k;
            const float w0 = sworb[d*NORB + o];
            const float w1 = sworb[(DF + d)*NORB + o];
            #pragma unroll
            for (int e = 0; e < 4; ++e) {
                const float xk = (&xa[e].x)[k];
                u[e] += xk * w0;
                v[e] += xk * w1;
            }
        }
    }

    // ---- envelope: Gram quadratic form, 4-ion groups; r: b128 broadcast ----
    float ea[4] = {0,0,0,0};
    #pragma unroll
    for (int ig = 0; ig < 4; ++ig) {
        float r[4][12];                       // statically indexed throughout
        #pragma unroll
        for (int e = 0; e < 4; ++e) {
            *(float4*)&r[e][0] = *(const float4*)(sr + (n0+e)*48 + ig*12 + 0);
            *(float4*)&r[e][4] = *(const float4*)(sr + (n0+e)*48 + ig*12 + 4);
            *(float4*)&r[e][8] = *(const float4*)(sr + (n0+e)*48 + ig*12 + 8);
        }
        #pragma unroll
        for (int ii = 0; ii < 4; ++ii) {
            const int i = ig*4 + ii;
            const float m0 = sM[(i*6 + 0)*NORB + o];
            const float m1 = sM[(i*6 + 1)*NORB + o];
            const float m2 = sM[(i*6 + 2)*NORB + o];
            const float m3 = sM[(i*6 + 3)*NORB + o];
            const float m4 = sM[(i*6 + 4)*NORB + o];
            const float m5 = sM[(i*6 + 5)*NORB + o];
            const float wi = swion[i];
            #pragma unroll
            for (int e = 0; e < 4; ++e) {
                const float r0 = r[e][ii*3 + 0];
                const float r1 = r[e][ii*3 + 1];
                const float r2 = r[e][ii*3 + 2];
                float d2 = m0*(r0*r0) + m1*(r1*r1) + m2*(r2*r2)
                         + m3*(r0*r1) + m4*(r0*r2) + m5*(r1*r2);
                ea[e] += wi * __expf(-sqrtf(fmaxf(d2, 0.f)));
            }
        }
    }

    // ---- write factors (wave: 2x128B segments per store) ----
    const float bo = b_orb[s*NORB + o];
    const size_t base = (size_t)blk * (NE*NORB);
    #pragma unroll
    for (int e = 0; e < 4; ++e) {
        const int idx = (n0 + e)*NORB + o;
        Uf[base + idx] = u[e];
        Ef[base + idx] = ea[e];
        Wf[base + idx] = (v[e] + bo) * ea[e];
    }
}

// ---------------------------------------------------------------------------
// K2: pure streaming expansion  out[p,i,o] = U[p,o]*E[i,o] + W[i,o]
// ---------------------------------------------------------------------------
__global__ __launch_bounds__(256) void k2_expand(
    const float* __restrict__ Uf,
    const float* __restrict__ Ef,
    const float* __restrict__ Wf,
    float* __restrict__ out)
{
    __shared__ float sU[NE][NORB];   // 4 KB
    const int t   = threadIdx.x;
    const int blk = blockIdx.x;
    const size_t base = (size_t)blk * (NE*NORB);

    ((float4*)&sU[0][0])[t] = ((const float4*)(Uf + base))[t];
    const float4 e4 = ((const float4*)(Ef + base))[t];
    const float4 w4 = ((const float4*)(Wf + base))[t];
    __syncthreads();

    const int o0 = (t & 7) * 4;
    float4* outp = (float4*)(out + (size_t)blk * (NE*NE*NORB));
    #pragma unroll
    for (int p = 0; p < NE; ++p) {
        const float4 u4 = *(const float4*)&sU[p][o0];
        float4 r;
        r.x = u4.x*e4.x + w4.x;
        r.y = u4.y*e4.y + w4.y;
        r.z = u4.z*e4.z + w4.z;
        r.w = u4.w*e4.w + w4.w;
        outp[p*256 + t] = r;
    }
}

// ---------------------------------------------------------------------------
// Fallback: proven single fused kernel (used only if ws is too small)
// ---------------------------------------------------------------------------
__global__ __launch_bounds__(256) void deq_orbital_fused(
    const float* __restrict__ x, const float* __restrict__ r_ei,
    const float* __restrict__ W_orb, const float* __restrict__ b_orb,
    const float* __restrict__ W_env, const float* __restrict__ w_ion,
    float* __restrict__ out)
{
    __shared__ float sx[NE][DF];
    __shared__ float sworb[2*DF][NORB];
    __shared__ float sr[NE][NION*3];
    __shared__ float swe[NION*3*NORB*3];
    __shared__ float sU[NE][NORB];
    __shared__ float sV[NE][NORB];
    __shared__ float sE[NE][NORB];
    __shared__ float sb[NORB];
    __shared__ float swion[NION];

    const int t   = threadIdx.x;
    const int blk = blockIdx.x;
    const int s   = blk >> 10;
    const int b   = blk & (BATCH - 1);

    {
        const float4* xg = (const float4*)(x + (size_t)(b*NELEC + s*NE) * DF);
        ((float4*)&sx[0][0])[t] = xg[t];
    }
    {
        const float4* wg = (const float4*)(W_orb + (size_t)s * 2*DF*NORB);
        float4* d = (float4*)&sworb[0][0];
        d[t] = wg[t]; d[t + 256] = wg[t + 256];
    }
    {
        const float4* rg = (const float4*)(r_ei + (size_t)(b*NELEC + s*NE) * NION * 3);
        float4* d = (float4*)&sr[0][0];
        d[t] = rg[t];
        if (t < 128) d[t + 256] = rg[t + 256];
    }
    {
        const float4* weg = (const float4*)(W_env + (size_t)s * NION*3*NORB*3);
        float4* d = (float4*)swe;
        for (int j = t; j < 1152; j += 256) d[j] = weg[j];
    }
    if (t < NORB) sb[t]    = b_orb[s*NORB + t];
    if (t < NION) swion[t] = w_ion[s*NION + t];
    __syncthreads();

    const int o  = t & 31;
    const int ng = t >> 5;
    float u_acc[4], v_acc[4];
    #pragma unroll
    for (int uu = 0; uu < 4; ++uu) { u_acc[uu] = 0.f; v_acc[uu] = 0.f; }
    #pragma unroll
    for (int d = 0; d < DF; ++d) {
        const float w0 = sworb[d][o];
        const float w1 = sworb[DF + d][o];
        #pragma unroll
        for (int uu = 0; uu < 4; ++uu) {
            const float xv = sx[ng*4 + uu][d];
            u_acc[uu] += xv * w0;
            v_acc[uu] += xv * w1;
        }
    }
    #pragma unroll
    for (int uu = 0; uu < 4; ++uu) {
        sU[ng*4 + uu][o] = u_acc[uu];
        sV[ng*4 + uu][o] = v_acc[uu];
    }
    #pragma unroll
    for (int uu = 0; uu < 4; ++uu) {
        const int nn = ng*4 + uu;
        float acc = 0.f;
        #pragma unroll
        for (int i = 0; i < NION; ++i) {
            const float r0 = sr[nn][i*3 + 0];
            const float r1 = sr[nn][i*3 + 1];
            const float r2 = sr[nn][i*3 + 2];
            const float* wp = &swe[i*3*NORB*3 + o*3];
            const float s0 = r0*wp[0] + r1*wp[NORB*3    ] + r2*wp[2*NORB*3    ];
            const float s1 = r0*wp[1] + r1*wp[NORB*3 + 1] + r2*wp[2*NORB*3 + 1];
            const float s2 = r0*wp[2] + r1*wp[NORB*3 + 2] + r2*wp[2*NORB*3 + 2];
            const float dist = sqrtf(s0*s0 + s1*s1 + s2*s2);
            acc += __expf(-dist) * swion[i];
        }
        sE[nn][o] = acc;
        sV[nn][o] = (v_acc[uu] + sb[o]) * acc;
    }
    __syncthreads();

    const int io = t >> 3;
    const int o0 = (t & 7) * 4;
    const float4 e4 = *(const float4*)&sE[io][o0];
    const float4 w4 = *(const float4*)&sV[io][o0];
    float4* outp = (float4*)(out + (size_t)blk * (NE*NE*NORB));
    #pragma unroll
    for (int p = 0; p < NE; ++p) {
        const float4 u4 = *(const float4*)&sU[p][o0];
        float4 r;
        r.x = u4.x*e4.x + w4.x;
        r.y = u4.y*e4.y + w4.y;
        r.z = u4.z*e4.z + w4.z;
        r.w = u4.w*e4.w + w4.w;
        outp[p*256 + t] = r;
    }
}

extern "C" void kernel_launch(void* const* d_in, const int* in_sizes, int n_in,
                              void* d_out, int out_size, void* d_ws, size_t ws_size,
                              hipStream_t stream) {
    const float* x     = (const float*)d_in[0];
    const float* r_ei  = (const float*)d_in[1];
    const float* W_orb = (const float*)d_in[2];
    const float* b_orb = (const float*)d_in[3];
    const float* W_env = (const float*)d_in[4];
    const float* w_ion = (const float*)d_in[5];
    float* out = (float*)d_out;

    if (ws_size >= WS_NEEDED) {
        float* Mg = (float*)d_ws;
        float* Uf = Mg + M_PAD;
        float* Ef = Uf + FACT_FLOATS;
        float* Wf = Ef + FACT_FLOATS;
        k0_gram<<<4, 256, 0, stream>>>(W_env, Mg);
        k1_factors<<<NSB, 256, 0, stream>>>(x, r_ei, W_orb, b_orb, w_ion, Mg,
                                            Uf, Ef, Wf);
        k2_expand<<<NSB, 256, 0, stream>>>(Uf, Ef, Wf, out);
    } else {
        deq_orbital_fused<<<NSB, 256, 0, stream>>>(x, r_ei, W_orb, b_orb,
                                                   W_env, w_ion, out);
    }
}